// Round 1
// baseline (24.215 us; speedup 1.0000x reference)
//
#include <hip/hip_runtime.h>

// TreeCrfLoss: pot = sum_i U[i, tl[i]]  (internal + leaf-child unary == every node once)
//            + sum_{c=1}^{N-1} E[c, tl[(c-1)/4], tl[c]]
// out = z - pot,  z = logsumexp(beliefs[0, 0:16])

#define NBLK 2048
#define NTHR 256

__global__ __launch_bounds__(NTHR) void tree_crf_partial(
    const float* __restrict__ U,      // [N,16]
    const float* __restrict__ E,      // [N,16,16]
    const int* __restrict__ tl,       // [N]
    float* __restrict__ partials,     // [NBLK]
    int N)
{
    int tid = blockIdx.x * NTHR + threadIdx.x;
    int stride = NBLK * NTHR;
    float acc = 0.0f;
    for (int i = tid; i < N; i += stride) {
        int l = tl[i];
        acc += U[(long)i * 16 + l];
        if (i >= 1) {
            int p = tl[(i - 1) >> 2];
            acc += E[((long)i << 8) + p * 16 + l];
        }
    }
    // 64-lane wave reduction
    #pragma unroll
    for (int off = 32; off > 0; off >>= 1)
        acc += __shfl_down(acc, off, 64);
    __shared__ float s[NTHR / 64];
    int lane = threadIdx.x & 63;
    int wave = threadIdx.x >> 6;
    if (lane == 0) s[wave] = acc;
    __syncthreads();
    if (threadIdx.x == 0) {
        float v = 0.0f;
        #pragma unroll
        for (int w = 0; w < NTHR / 64; ++w) v += s[w];
        partials[blockIdx.x] = v;
    }
}

__global__ __launch_bounds__(NTHR) void tree_crf_finalize(
    const float* __restrict__ beliefs,   // [N,16], only row 0 used
    const float* __restrict__ partials,  // [NBLK]
    float* __restrict__ out)
{
    float acc = 0.0f;
    for (int i = threadIdx.x; i < NBLK; i += NTHR)
        acc += partials[i];
    #pragma unroll
    for (int off = 32; off > 0; off >>= 1)
        acc += __shfl_down(acc, off, 64);
    __shared__ float s[NTHR / 64];
    int lane = threadIdx.x & 63;
    int wave = threadIdx.x >> 6;
    if (lane == 0) s[wave] = acc;
    __syncthreads();
    if (threadIdx.x == 0) {
        float pot = 0.0f;
        #pragma unroll
        for (int w = 0; w < NTHR / 64; ++w) pot += s[w];
        // z = logsumexp(beliefs[0..15]) — 16 scalars, trivial
        float m = beliefs[0];
        #pragma unroll
        for (int j = 1; j < 16; ++j) m = fmaxf(m, beliefs[j]);
        float se = 0.0f;
        #pragma unroll
        for (int j = 0; j < 16; ++j) se += __expf(beliefs[j] - m);
        float z = m + __logf(se);
        out[0] = z - pot;   // -(pot - z)
    }
}

extern "C" void kernel_launch(void* const* d_in, const int* in_sizes, int n_in,
                              void* d_out, int out_size, void* d_ws, size_t ws_size,
                              hipStream_t stream) {
    const float* U       = (const float*)d_in[0];   // unary_potentials [N,16]
    const float* E       = (const float*)d_in[1];   // edge_potentials [N,16,16]
    const float* beliefs = (const float*)d_in[2];   // beliefs [N,16]
    const int*   tl      = (const int*)d_in[3];     // true_labels [N]
    int N = in_sizes[3];

    float* partials = (float*)d_ws;   // NBLK floats, fully overwritten each call
    float* out      = (float*)d_out;

    tree_crf_partial<<<NBLK, NTHR, 0, stream>>>(U, E, tl, partials, N);
    tree_crf_finalize<<<1, NTHR, 0, stream>>>(beliefs, partials, out);
}

// Round 2
// 21.420 us; speedup vs baseline: 1.1305x; 1.1305x over previous
//
#include <hip/hip_runtime.h>

// TreeCrfLoss: pot = sum_i U[i, tl[i]]           (unary term covers every node exactly once)
//            + sum_{c=1}^{N-1} E[c, tl[(c-1)/4], tl[c]]
// out = z - pot,  z = logsumexp(beliefs[0, 0:16])
//
// Thread t handles nodes 4t..4t+3. K-ary (K=4) tree => nodes 4t+1..4t+3 have parent t,
// node 4t has parent t-1. Labels for the quad load as one aligned int4.

#define NTHR 256

__global__ __launch_bounds__(NTHR) void tree_crf_partial(
    const float* __restrict__ U,      // [N,16]
    const float* __restrict__ E,      // [N,16,16]
    const int* __restrict__ tl,       // [N]
    float* __restrict__ partials,     // [gridDim.x]
    int N)
{
    const int tid = blockIdx.x * NTHR + threadIdx.x;
    const int Nq  = N >> 2;           // full quads
    float acc = 0.0f;

    if (tid < Nq) {
        const int base = tid << 2;    // base..base+3 all < N
        const int4 l4 = *reinterpret_cast<const int4*>(tl + base);
        // parent labels: node base (=4t) -> tid-1 ; nodes base+1..3 -> tid
        const int plB = tl[tid];                      // parent label for 4t+1..4t+3
        const int plA = (tid > 0) ? tl[tid - 1] : 0;  // parent label for 4t (unused at t=0)

        // 4 unary gathers (independent)
        float u0 = __builtin_nontemporal_load(&U[((size_t)base + 0) * 16 + l4.x]);
        float u1 = __builtin_nontemporal_load(&U[((size_t)base + 1) * 16 + l4.y]);
        float u2 = __builtin_nontemporal_load(&U[((size_t)base + 2) * 16 + l4.z]);
        float u3 = __builtin_nontemporal_load(&U[((size_t)base + 3) * 16 + l4.w]);

        // 4 edge gathers (independent). Node 0 has no incoming edge.
        float e0 = 0.0f;
        if (tid > 0)
            e0 = __builtin_nontemporal_load(&E[(((size_t)base + 0) << 8) + plA * 16 + l4.x]);
        float e1 = __builtin_nontemporal_load(&E[(((size_t)base + 1) << 8) + plB * 16 + l4.y]);
        float e2 = __builtin_nontemporal_load(&E[(((size_t)base + 2) << 8) + plB * 16 + l4.z]);
        float e3 = __builtin_nontemporal_load(&E[(((size_t)base + 3) << 8) + plB * 16 + l4.w]);

        acc = ((u0 + u1) + (u2 + u3)) + ((e0 + e1) + (e2 + e3));
    } else if (tid == Nq && (N & 3)) {
        // tail nodes (generic safety; N=500000 has none)
        for (int n = Nq << 2; n < N; ++n) {
            int l = tl[n];
            acc += U[(size_t)n * 16 + l];
            if (n >= 1) {
                int p = tl[(n - 1) >> 2];
                acc += E[((size_t)n << 8) + p * 16 + l];
            }
        }
    }

    // 64-lane wave reduction
    #pragma unroll
    for (int off = 32; off > 0; off >>= 1)
        acc += __shfl_down(acc, off, 64);
    __shared__ float s[NTHR / 64];
    const int lane = threadIdx.x & 63;
    const int wave = threadIdx.x >> 6;
    if (lane == 0) s[wave] = acc;
    __syncthreads();
    if (threadIdx.x == 0) {
        float v = 0.0f;
        #pragma unroll
        for (int w = 0; w < NTHR / 64; ++w) v += s[w];
        partials[blockIdx.x] = v;
    }
}

__global__ __launch_bounds__(NTHR) void tree_crf_finalize(
    const float* __restrict__ beliefs,   // [N,16], only row 0 used
    const float* __restrict__ partials,  // [nb]
    float* __restrict__ out,
    int nb)
{
    float acc = 0.0f;
    for (int i = threadIdx.x; i < nb; i += NTHR)
        acc += partials[i];
    #pragma unroll
    for (int off = 32; off > 0; off >>= 1)
        acc += __shfl_down(acc, off, 64);
    __shared__ float s[NTHR / 64];
    const int lane = threadIdx.x & 63;
    const int wave = threadIdx.x >> 6;
    if (lane == 0) s[wave] = acc;
    __syncthreads();
    if (threadIdx.x == 0) {
        float pot = 0.0f;
        #pragma unroll
        for (int w = 0; w < NTHR / 64; ++w) pot += s[w];
        float m = beliefs[0];
        #pragma unroll
        for (int j = 1; j < 16; ++j) m = fmaxf(m, beliefs[j]);
        float se = 0.0f;
        #pragma unroll
        for (int j = 0; j < 16; ++j) se += __expf(beliefs[j] - m);
        float z = m + __logf(se);
        out[0] = z - pot;   // -(pot - z)
    }
}

extern "C" void kernel_launch(void* const* d_in, const int* in_sizes, int n_in,
                              void* d_out, int out_size, void* d_ws, size_t ws_size,
                              hipStream_t stream) {
    const float* U       = (const float*)d_in[0];   // unary_potentials [N,16]
    const float* E       = (const float*)d_in[1];   // edge_potentials [N,16,16]
    const float* beliefs = (const float*)d_in[2];   // beliefs [N,16]
    const int*   tl      = (const int*)d_in[3];     // true_labels [N]
    const int N = in_sizes[3];

    const int Nq = N >> 2;
    const int threads_needed = Nq + ((N & 3) ? 1 : 0);
    const int nb = (threads_needed + NTHR - 1) / NTHR;   // 489 for N=500000

    float* partials = (float*)d_ws;   // nb floats, fully overwritten each call
    float* out      = (float*)d_out;

    tree_crf_partial<<<nb, NTHR, 0, stream>>>(U, E, tl, partials, N);
    tree_crf_finalize<<<1, NTHR, 0, stream>>>(beliefs, partials, out, nb);
}